// Round 1
// baseline (341.667 us; speedup 1.0000x reference)
//
#include <hip/hip_runtime.h>
#include <stdint.h>

// WhaleAttention: B=2 N=2048 C=1024 H=16 D=64
// Pipeline: cast->proj GEMMs(bf16 MFMA)->LN/layout posts->flash attn(K=128 concat)->out GEMM

typedef short short8 __attribute__((ext_vector_type(8)));
typedef float f32x4 __attribute__((ext_vector_type(4)));
typedef unsigned short us4 __attribute__((ext_vector_type(4)));
typedef unsigned short u16;

#define NB 2
#define NN 2048
#define NC 1024
#define NH 16
#define ND 64

__device__ __forceinline__ u16 f2bf(float f) {
    unsigned int u = __float_as_uint(f);
    u += 0x7fffu + ((u >> 16) & 1u);
    return (u16)(u >> 16);
}

// ---------------- cast fp32 -> bf16 ----------------
__global__ __launch_bounds__(256) void cast_kernel(const float* __restrict__ src,
                                                   u16* __restrict__ dst, int n4) {
    int i = blockIdx.x * 256 + threadIdx.x;
    if (i < n4) {
        float4 f = reinterpret_cast<const float4*>(src)[i];
        us4 o;
        o[0] = f2bf(f.x); o[1] = f2bf(f.y); o[2] = f2bf(f.z); o[3] = f2bf(f.w);
        reinterpret_cast<us4*>(dst)[i] = o;
    }
}

// ---------------- GEMM C = A @ W^T (+bias), A[4096][1024] bf16, W[1024][1024] bf16, out fp32 ----------------
__device__ __forceinline__ void gemm_bt_body(const u16* __restrict__ A,
                                             const u16* __restrict__ W,
                                             float* __restrict__ out,
                                             const float* __restrict__ bias,
                                             int m0, int n0) {
    __shared__ u16 As[128 * 32];
    __shared__ u16 Bs[128 * 32];
    int t = threadIdx.x, lane = t & 63, w = t >> 6;
    int wm = (w >> 1) * 64, wn = (w & 1) * 64;
    int lr = lane & 15, lg = lane >> 4;
    f32x4 acc[4][4] = {};
    for (int kk = 0; kk < 1024; kk += 32) {
#pragma unroll
        for (int i = 0; i < 2; i++) {
            int chunk = i * 256 + t;
            int row = chunk >> 2, c8 = (chunk & 3) * 8;
            *reinterpret_cast<short8*>(As + row * 32 + c8) =
                *reinterpret_cast<const short8*>(A + (size_t)(m0 + row) * 1024 + kk + c8);
            *reinterpret_cast<short8*>(Bs + row * 32 + c8) =
                *reinterpret_cast<const short8*>(W + (size_t)(n0 + row) * 1024 + kk + c8);
        }
        __syncthreads();
        short8 af[4], bw[4];
#pragma unroll
        for (int mt = 0; mt < 4; mt++)
            af[mt] = *reinterpret_cast<const short8*>(As + (wm + mt * 16 + lr) * 32 + lg * 8);
#pragma unroll
        for (int nt = 0; nt < 4; nt++)
            bw[nt] = *reinterpret_cast<const short8*>(Bs + (wn + nt * 16 + lr) * 32 + lg * 8);
#pragma unroll
        for (int mt = 0; mt < 4; mt++)
#pragma unroll
            for (int nt = 0; nt < 4; nt++)
                acc[mt][nt] = __builtin_amdgcn_mfma_f32_16x16x32_bf16(af[mt], bw[nt], acc[mt][nt], 0, 0, 0);
        __syncthreads();
    }
#pragma unroll
    for (int mt = 0; mt < 4; mt++) {
#pragma unroll
        for (int nt = 0; nt < 4; nt++) {
            int c = n0 + wn + nt * 16 + lr;
            float badd = bias ? bias[c] : 0.0f;
            int r = m0 + wm + mt * 16 + lg * 4;
#pragma unroll
            for (int rg = 0; rg < 4; rg++)
                out[(size_t)(r + rg) * 1024 + c] = acc[mt][nt][rg] + badd;
        }
    }
}

// z=0:q(bq) 1:k(bk) 2:v(bv) 3:p(none, A=pos)
__global__ __launch_bounds__(256) void proj_gemm(const u16* __restrict__ xbf,
                                                 const u16* __restrict__ posbf,
                                                 const u16* __restrict__ Wbase,
                                                 float* __restrict__ prebase,
                                                 const float* __restrict__ bq,
                                                 const float* __restrict__ bk,
                                                 const float* __restrict__ bv) {
    int z = blockIdx.z;
    const u16* A = (z == 3) ? posbf : xbf;
    const u16* W = Wbase + (size_t)z * 1048576;
    float* out = prebase + (size_t)z * 4194304;
    const float* bias = (z == 0) ? bq : ((z == 1) ? bk : ((z == 2) ? bv : (const float*)nullptr));
    gemm_bt_body(A, W, out, bias, blockIdx.y * 128, blockIdx.x * 128);
}

__global__ __launch_bounds__(256) void out_gemm(const u16* __restrict__ ctx,
                                                const u16* __restrict__ Wo,
                                                float* __restrict__ out,
                                                const float* __restrict__ bo) {
    gemm_bt_body(ctx, Wo, out, bo, blockIdx.y * 128, blockIdx.x * 128);
}

// ---------------- LN on q/k rows, write QQ=[q^+u | q^+v], KK[:,0:64]=k^ ----------------
__global__ __launch_bounds__(256) void post_qk(const float* __restrict__ prebase,
                                               const float* __restrict__ qw, const float* __restrict__ qb,
                                               const float* __restrict__ kw, const float* __restrict__ kb,
                                               const float* __restrict__ pbu, const float* __restrict__ pbv,
                                               u16* __restrict__ QQ, u16* __restrict__ KK) {
    int isq = (blockIdx.y == 0);
    const float* pre = prebase + (isq ? 0 : (size_t)4194304);
    const float* lw = isq ? qw : kw;
    const float* lb = isq ? qb : kb;
    int wv = threadIdx.x >> 6, lane = threadIdx.x & 63;
    int row = blockIdx.x * 4 + wv;   // 0..4095
    int b = row >> 11, n = row & 2047;
    const float* pr = pre + (size_t)row * 1024;
    float vals[16];
    float s = 0.f, s2 = 0.f;
#pragma unroll
    for (int i = 0; i < 4; i++) {
        float4 f = *reinterpret_cast<const float4*>(pr + i * 256 + lane * 4);
        vals[i * 4 + 0] = f.x; vals[i * 4 + 1] = f.y; vals[i * 4 + 2] = f.z; vals[i * 4 + 3] = f.w;
        s += f.x + f.y + f.z + f.w;
        s2 += f.x * f.x + f.y * f.y + f.z * f.z + f.w * f.w;
    }
#pragma unroll
    for (int m = 1; m < 64; m <<= 1) { s += __shfl_xor(s, m); s2 += __shfl_xor(s2, m); }
    float mean = s * (1.f / 1024.f);
    float var = s2 * (1.f / 1024.f) - mean * mean;
    float inv = rsqrtf(var + 1e-6f);
#pragma unroll
    for (int i = 0; i < 4; i++) {
        int c0 = i * 256 + lane * 4;
        int h = c0 >> 6, d0 = c0 & 63;
        size_t base = ((size_t)(b * NH + h) * NN + n) * 128 + d0;
        if (isq) {
            us4 u0, u1;
#pragma unroll
            for (int j = 0; j < 4; j++) {
                float xn = (vals[i * 4 + j] - mean) * inv * lw[c0 + j] + lb[c0 + j];
                u0[j] = f2bf(xn + pbu[h * 64 + d0 + j]);
                u1[j] = f2bf(xn + pbv[h * 64 + d0 + j]);
            }
            *reinterpret_cast<us4*>(QQ + base) = u0;
            *reinterpret_cast<us4*>(QQ + base + 64) = u1;
        } else {
            us4 u0;
#pragma unroll
            for (int j = 0; j < 4; j++) {
                float xn = (vals[i * 4 + j] - mean) * inv * lw[c0 + j] + lb[c0 + j];
                u0[j] = f2bf(xn);
            }
            *reinterpret_cast<us4*>(KK + base) = u0;
        }
    }
}

// ---------------- v -> Vt[b][h][d][n] (bias already in GEMM), p -> KK[:,64:128] ----------------
__global__ __launch_bounds__(256) void post_vp(const float* __restrict__ vpre,
                                               const float* __restrict__ ppre,
                                               u16* __restrict__ Vt, u16* __restrict__ KK) {
    __shared__ u16 tile[64][66];
    int bh = blockIdx.x;               // 0..31
    int b = bh >> 4, h = bh & 15;
    int n0 = blockIdx.y * 64;
    int t = threadIdx.x, lane = t & 63, w = t >> 6;
#pragma unroll
    for (int j = 0; j < 4; j++) {
        int nr = t >> 2;                 // 0..63
        int d = (t & 3) * 16 + j * 4;    // 0..63
        size_t goff = ((size_t)(b * NN + n0 + nr)) * 1024 + h * 64 + d;
        float4 fv = *reinterpret_cast<const float4*>(vpre + goff);
        tile[nr][d + 0] = f2bf(fv.x);
        tile[nr][d + 1] = f2bf(fv.y);
        tile[nr][d + 2] = f2bf(fv.z);
        tile[nr][d + 3] = f2bf(fv.w);
        float4 fp = *reinterpret_cast<const float4*>(ppre + goff);
        us4 up; up[0] = f2bf(fp.x); up[1] = f2bf(fp.y); up[2] = f2bf(fp.z); up[3] = f2bf(fp.w);
        *reinterpret_cast<us4*>(KK + ((size_t)(b * NH + h) * NN + n0 + nr) * 128 + 64 + d) = up;
    }
    __syncthreads();
    size_t vbase = (size_t)(b * NH + h) * 64 * NN;
#pragma unroll
    for (int j = 0; j < 16; j++) {
        int d = w + j * 4;
        Vt[vbase + (size_t)d * NN + n0 + lane] = tile[lane][d];
    }
}

// ---------------- flash attention: S = QQ·KK^T (K=128), softmax, O = P·V ----------------
__global__ __launch_bounds__(256) void flash_attn(const u16* __restrict__ QQ,
                                                  const u16* __restrict__ KK,
                                                  const u16* __restrict__ Vt,
                                                  u16* __restrict__ ctx) {
    __shared__ u16 KKs[128 * 128];
    __shared__ u16 Vts[64 * 128];
    __shared__ u16 Ps[4][32 * 128];
    int qt = blockIdx.x, h = blockIdx.y, b = blockIdx.z;
    int n0 = qt * 128;
    int t = threadIdx.x, lane = t & 63, w = t >> 6;
    int lr = lane & 15, lg = lane >> 4;
    const u16* QQg = QQ + ((size_t)(b * NH + h) * NN) * 128;
    const u16* KKg = KK + ((size_t)(b * NH + h) * NN) * 128;
    const u16* Vtg = Vt + ((size_t)(b * NH + h) * 64) * NN;

    // load Q tile (reuse KKs), pull per-wave A-fragments into registers
#pragma unroll
    for (int i = 0; i < 8; i++) {
        int chunk = i * 256 + t;
        int row = chunk >> 4, c8 = (chunk & 15) * 8;
        *reinterpret_cast<short8*>(KKs + row * 128 + c8) =
            *reinterpret_cast<const short8*>(QQg + (size_t)(n0 + row) * 128 + c8);
    }
    __syncthreads();
    short8 aq[2][4];
#pragma unroll
    for (int rt = 0; rt < 2; rt++)
#pragma unroll
        for (int ks = 0; ks < 4; ks++)
            aq[rt][ks] = *reinterpret_cast<const short8*>(KKs + (w * 32 + rt * 16 + lr) * 128 + ks * 32 + lg * 8);
    __syncthreads();

    f32x4 O[2][4] = {};
    float mrun[2][4], lrun[2][4];
#pragma unroll
    for (int rt = 0; rt < 2; rt++)
#pragma unroll
        for (int rg = 0; rg < 4; rg++) { mrun[rt][rg] = -1e30f; lrun[rt][rg] = 0.f; }

    for (int m0 = 0; m0 < NN; m0 += 128) {
#pragma unroll
        for (int i = 0; i < 8; i++) {
            int chunk = i * 256 + t;
            int row = chunk >> 4, c8 = (chunk & 15) * 8;
            *reinterpret_cast<short8*>(KKs + row * 128 + c8) =
                *reinterpret_cast<const short8*>(KKg + (size_t)(m0 + row) * 128 + c8);
        }
#pragma unroll
        for (int i = 0; i < 4; i++) {
            int chunk = i * 256 + t;
            int row = chunk >> 4, c8 = (chunk & 15) * 8;
            *reinterpret_cast<short8*>(Vts + row * 128 + c8) =
                *reinterpret_cast<const short8*>(Vtg + (size_t)row * NN + m0 + c8);
        }
        __syncthreads();
        // S = QQ·KK^T  (32 rows per wave x 128 cols)
        f32x4 S[2][8];
#pragma unroll
        for (int ct = 0; ct < 8; ct++) {
            short8 bk[4];
#pragma unroll
            for (int ks = 0; ks < 4; ks++)
                bk[ks] = *reinterpret_cast<const short8*>(KKs + (ct * 16 + lr) * 128 + ks * 32 + lg * 8);
#pragma unroll
            for (int rt = 0; rt < 2; rt++) {
                f32x4 s = {};
#pragma unroll
                for (int ks = 0; ks < 4; ks++)
                    s = __builtin_amdgcn_mfma_f32_16x16x32_bf16(aq[rt][ks], bk[ks], s, 0, 0, 0);
                S[rt][ct] = s;
            }
        }
        // online softmax; rows owned by (lg, rg, rt); reduce over col lanes (lr bits)
#pragma unroll
        for (int rt = 0; rt < 2; rt++) {
#pragma unroll
            for (int rg = 0; rg < 4; rg++) {
                float mx = -1e30f;
#pragma unroll
                for (int ct = 0; ct < 8; ct++) mx = fmaxf(mx, S[rt][ct][rg]);
#pragma unroll
                for (int mk = 1; mk < 16; mk <<= 1) mx = fmaxf(mx, __shfl_xor(mx, mk));
                mx *= 0.125f;
                float newm = fmaxf(mrun[rt][rg], mx);
                float sf = __expf(mrun[rt][rg] - newm);
                float ls = 0.f;
#pragma unroll
                for (int ct = 0; ct < 8; ct++) {
                    float p = __expf(S[rt][ct][rg] * 0.125f - newm);
                    S[rt][ct][rg] = p;
                    ls += p;
                }
#pragma unroll
                for (int mk = 1; mk < 16; mk <<= 1) ls += __shfl_xor(ls, mk);
                lrun[rt][rg] = lrun[rt][rg] * sf + ls;
                mrun[rt][rg] = newm;
#pragma unroll
                for (int dt = 0; dt < 4; dt++) O[rt][dt][rg] *= sf;
            }
        }
        // P -> per-wave LDS strip (C/D layout -> row-major)
        u16* Pw = Ps[w];
#pragma unroll
        for (int rt = 0; rt < 2; rt++)
#pragma unroll
            for (int ct = 0; ct < 8; ct++)
#pragma unroll
                for (int rg = 0; rg < 4; rg++)
                    Pw[(rt * 16 + lg * 4 + rg) * 128 + ct * 16 + lr] = f2bf(S[rt][ct][rg]);
        // O += P·V
        short8 pa[2][4];
#pragma unroll
        for (int rt = 0; rt < 2; rt++)
#pragma unroll
            for (int ks = 0; ks < 4; ks++)
                pa[rt][ks] = *reinterpret_cast<const short8*>(Pw + (rt * 16 + lr) * 128 + ks * 32 + lg * 8);
#pragma unroll
        for (int dt = 0; dt < 4; dt++) {
            short8 vf[4];
#pragma unroll
            for (int ks = 0; ks < 4; ks++)
                vf[ks] = *reinterpret_cast<const short8*>(Vts + (dt * 16 + lr) * 128 + ks * 32 + lg * 8);
#pragma unroll
            for (int rt = 0; rt < 2; rt++) {
                f32x4 o = O[rt][dt];
#pragma unroll
                for (int ks = 0; ks < 4; ks++)
                    o = __builtin_amdgcn_mfma_f32_16x16x32_bf16(pa[rt][ks], vf[ks], o, 0, 0, 0);
                O[rt][dt] = o;
            }
        }
        __syncthreads();
    }
    // epilogue: normalize, write ctx [B*N][C] bf16
#pragma unroll
    for (int rt = 0; rt < 2; rt++) {
#pragma unroll
        for (int dt = 0; dt < 4; dt++) {
#pragma unroll
            for (int rg = 0; rg < 4; rg++) {
                int n = n0 + w * 32 + rt * 16 + lg * 4 + rg;
                float oo = O[rt][dt][rg] / lrun[rt][rg];
                ctx[((size_t)(b * NN) + n) * 1024 + h * 64 + dt * 16 + lr] = f2bf(oo);
            }
        }
    }
}

extern "C" void kernel_launch(void* const* d_in, const int* in_sizes, int n_in,
                              void* d_out, int out_size, void* d_ws, size_t ws_size,
                              hipStream_t stream) {
    const float* x   = (const float*)d_in[0];
    const float* pos = (const float*)d_in[2];
    const float* Wq  = (const float*)d_in[3];
    const float* bq  = (const float*)d_in[4];
    const float* Wk  = (const float*)d_in[5];
    const float* bk  = (const float*)d_in[6];
    const float* Wv  = (const float*)d_in[7];
    const float* bv  = (const float*)d_in[8];
    const float* Wo  = (const float*)d_in[9];
    const float* bo  = (const float*)d_in[10];
    const float* qlw = (const float*)d_in[11];
    const float* qlb = (const float*)d_in[12];
    const float* klw = (const float*)d_in[13];
    const float* klb = (const float*)d_in[14];
    const float* Wp  = (const float*)d_in[15];
    const float* pbu = (const float*)d_in[16];
    const float* pbv = (const float*)d_in[17];
    float* out = (float*)d_out;

    char* ws = (char*)d_ws;
    u16*   xbf   = (u16*)(ws);                      //  8388608 B
    u16*   posbf = (u16*)(ws + 8388608);            //  8388608 B
    u16*   Wbf   = (u16*)(ws + 16777216);           //  5 x 2097152 B (q,k,v,p,o)
    float* pre   = (float*)(ws + 27262976);         //  4 x 16777216 B (q,k,v,p)
    u16*   QQ    = (u16*)(ws + 94371840);           // 16777216 B
    u16*   KK    = (u16*)(ws + 111149056);          // 16777216 B
    u16*   Vt    = (u16*)(ws + 127926272);          //  8388608 B
    u16*   ctx   = (u16*)(ws + 136314880);          //  8388608 B  (total 144703488)

    cast_kernel<<<4096, 256, 0, stream>>>(x, xbf, 1048576);
    cast_kernel<<<4096, 256, 0, stream>>>(pos, posbf, 1048576);
    cast_kernel<<<1024, 256, 0, stream>>>(Wq, Wbf + 0 * 1048576, 262144);
    cast_kernel<<<1024, 256, 0, stream>>>(Wk, Wbf + 1 * 1048576, 262144);
    cast_kernel<<<1024, 256, 0, stream>>>(Wv, Wbf + 2 * 1048576, 262144);
    cast_kernel<<<1024, 256, 0, stream>>>(Wp, Wbf + 3 * 1048576, 262144);
    cast_kernel<<<1024, 256, 0, stream>>>(Wo, Wbf + 4 * 1048576, 262144);

    proj_gemm<<<dim3(8, 32, 4), 256, 0, stream>>>(xbf, posbf, Wbf, pre, bq, bk, bv);
    post_qk<<<dim3(1024, 2), 256, 0, stream>>>(pre, qlw, qlb, klw, klb, pbu, pbv, QQ, KK);
    post_vp<<<dim3(32, 32), 256, 0, stream>>>(pre + (size_t)2 * 4194304, pre + (size_t)3 * 4194304, Vt, KK);
    flash_attn<<<dim3(16, 16, 2), 256, 0, stream>>>(QQ, KK, Vt, ctx);
    out_gemm<<<dim3(8, 32), 256, 0, stream>>>(ctx, Wbf + 4 * 1048576, out, bo);
}

// Round 3
// 275.414 us; speedup vs baseline: 1.2406x; 1.2406x over previous
//
#include <hip/hip_runtime.h>
#include <stdint.h>

// WhaleAttention: B=2 N=2048 C=1024 H=16 D=64
// R2 (resubmit after infra failure): flash LDS bank-conflict fix via pre-swizzled global
// (XOR 16B-chunk, keyed row&7), global_load_lds staging, P strip halved -> 64KB LDS
// (2 blocks/CU), SCALE folded into Q.

typedef short short8 __attribute__((ext_vector_type(8)));
typedef float f32x4 __attribute__((ext_vector_type(4)));
typedef unsigned short us4 __attribute__((ext_vector_type(4)));
typedef unsigned short u16;

#define NB 2
#define NN 2048
#define NC 1024
#define NH 16
#define ND 64

__device__ __forceinline__ u16 f2bf(float f) {
    unsigned int u = __float_as_uint(f);
    u += 0x7fffu + ((u >> 16) & 1u);
    return (u16)(u >> 16);
}

// swizzled column for a 128-u16 row: permute 16B chunks by XOR(row&7). involution.
__device__ __forceinline__ int swzc(int row, int c) {
    return (((c >> 3) ^ (row & 7)) << 3) | (c & 7);
}

__device__ __forceinline__ void gload16(const void* g, void* l) {
    __builtin_amdgcn_global_load_lds(
        (const __attribute__((address_space(1))) unsigned int*)g,
        (__attribute__((address_space(3))) unsigned int*)l, 16, 0, 0);
}

// ---------------- cast fp32 -> bf16 ----------------
__global__ __launch_bounds__(256) void cast_kernel(const float* __restrict__ src,
                                                   u16* __restrict__ dst, int n4) {
    int i = blockIdx.x * 256 + threadIdx.x;
    if (i < n4) {
        float4 f = reinterpret_cast<const float4*>(src)[i];
        us4 o;
        o[0] = f2bf(f.x); o[1] = f2bf(f.y); o[2] = f2bf(f.z); o[3] = f2bf(f.w);
        reinterpret_cast<us4*>(dst)[i] = o;
    }
}

// ---------------- GEMM C = A @ W^T (+bias), out fp32 ----------------
__device__ __forceinline__ void gemm_bt_body(const u16* __restrict__ A,
                                             const u16* __restrict__ W,
                                             float* __restrict__ out,
                                             const float* __restrict__ bias,
                                             int m0, int n0) {
    __shared__ u16 As[128 * 32];
    __shared__ u16 Bs[128 * 32];
    int t = threadIdx.x, lane = t & 63, w = t >> 6;
    int wm = (w >> 1) * 64, wn = (w & 1) * 64;
    int lr = lane & 15, lg = lane >> 4;
    f32x4 acc[4][4] = {};
    for (int kk = 0; kk < 1024; kk += 32) {
#pragma unroll
        for (int i = 0; i < 2; i++) {
            int chunk = i * 256 + t;
            int row = chunk >> 2, c8 = (chunk & 3) * 8;
            *reinterpret_cast<short8*>(As + row * 32 + c8) =
                *reinterpret_cast<const short8*>(A + (size_t)(m0 + row) * 1024 + kk + c8);
            *reinterpret_cast<short8*>(Bs + row * 32 + c8) =
                *reinterpret_cast<const short8*>(W + (size_t)(n0 + row) * 1024 + kk + c8);
        }
        __syncthreads();
        short8 af[4], bw[4];
#pragma unroll
        for (int mt = 0; mt < 4; mt++)
            af[mt] = *reinterpret_cast<const short8*>(As + (wm + mt * 16 + lr) * 32 + lg * 8);
#pragma unroll
        for (int nt = 0; nt < 4; nt++)
            bw[nt] = *reinterpret_cast<const short8*>(Bs + (wn + nt * 16 + lr) * 32 + lg * 8);
#pragma unroll
        for (int mt = 0; mt < 4; mt++)
#pragma unroll
            for (int nt = 0; nt < 4; nt++)
                acc[mt][nt] = __builtin_amdgcn_mfma_f32_16x16x32_bf16(af[mt], bw[nt], acc[mt][nt], 0, 0, 0);
        __syncthreads();
    }
#pragma unroll
    for (int mt = 0; mt < 4; mt++) {
#pragma unroll
        for (int nt = 0; nt < 4; nt++) {
            int c = n0 + wn + nt * 16 + lr;
            float badd = bias ? bias[c] : 0.0f;
            int r = m0 + wm + mt * 16 + lg * 4;
#pragma unroll
            for (int rg = 0; rg < 4; rg++)
                out[(size_t)(r + rg) * 1024 + c] = acc[mt][nt][rg] + badd;
        }
    }
}

// z=0:q(bq) 1:k(bk) 2:v(bv) 3:p(none, A=pos)
__global__ __launch_bounds__(256) void proj_gemm(const u16* __restrict__ xbf,
                                                 const u16* __restrict__ posbf,
                                                 const u16* __restrict__ Wbase,
                                                 float* __restrict__ prebase,
                                                 const float* __restrict__ bq,
                                                 const float* __restrict__ bk,
                                                 const float* __restrict__ bv) {
    int z = blockIdx.z;
    const u16* A = (z == 3) ? posbf : xbf;
    const u16* W = Wbase + (size_t)z * 1048576;
    float* out = prebase + (size_t)z * 4194304;
    const float* bias = (z == 0) ? bq : ((z == 1) ? bk : ((z == 2) ? bv : (const float*)nullptr));
    gemm_bt_body(A, W, out, bias, blockIdx.y * 128, blockIdx.x * 128);
}

__global__ __launch_bounds__(256) void out_gemm(const u16* __restrict__ ctx,
                                                const u16* __restrict__ Wo,
                                                float* __restrict__ out,
                                                const float* __restrict__ bo) {
    gemm_bt_body(ctx, Wo, out, bo, blockIdx.y * 128, blockIdx.x * 128);
}

// ---------------- LN on q/k rows; QQ=[0.125*(q^+u) | 0.125*(q^+v)], KK[:,0:64]=k^  (pre-swizzled) ----------------
__global__ __launch_bounds__(256) void post_qk(const float* __restrict__ prebase,
                                               const float* __restrict__ qw, const float* __restrict__ qb,
                                               const float* __restrict__ kw, const float* __restrict__ kb,
                                               const float* __restrict__ pbu, const float* __restrict__ pbv,
                                               u16* __restrict__ QQ, u16* __restrict__ KK) {
    int isq = (blockIdx.y == 0);
    const float* pre = prebase + (isq ? 0 : (size_t)4194304);
    const float* lw = isq ? qw : kw;
    const float* lb = isq ? qb : kb;
    int wv = threadIdx.x >> 6, lane = threadIdx.x & 63;
    int row = blockIdx.x * 4 + wv;   // 0..4095
    int b = row >> 11, n = row & 2047;
    const float* pr = pre + (size_t)row * 1024;
    float vals[16];
    float s = 0.f, s2 = 0.f;
#pragma unroll
    for (int i = 0; i < 4; i++) {
        float4 f = *reinterpret_cast<const float4*>(pr + i * 256 + lane * 4);
        vals[i * 4 + 0] = f.x; vals[i * 4 + 1] = f.y; vals[i * 4 + 2] = f.z; vals[i * 4 + 3] = f.w;
        s += f.x + f.y + f.z + f.w;
        s2 += f.x * f.x + f.y * f.y + f.z * f.z + f.w * f.w;
    }
#pragma unroll
    for (int m = 1; m < 64; m <<= 1) { s += __shfl_xor(s, m); s2 += __shfl_xor(s2, m); }
    float mean = s * (1.f / 1024.f);
    float var = s2 * (1.f / 1024.f) - mean * mean;
    float inv = rsqrtf(var + 1e-6f);
#pragma unroll
    for (int i = 0; i < 4; i++) {
        int c0 = i * 256 + lane * 4;
        int h = c0 >> 6, d0 = c0 & 63;
        size_t base = ((size_t)(b * NH + h) * NN + n) * 128;
        if (isq) {
            us4 u0, u1;
#pragma unroll
            for (int j = 0; j < 4; j++) {
                float xn = (vals[i * 4 + j] - mean) * inv * lw[c0 + j] + lb[c0 + j];
                u0[j] = f2bf((xn + pbu[h * 64 + d0 + j]) * 0.125f);
                u1[j] = f2bf((xn + pbv[h * 64 + d0 + j]) * 0.125f);
            }
            *reinterpret_cast<us4*>(QQ + base + swzc(n, d0)) = u0;
            *reinterpret_cast<us4*>(QQ + base + swzc(n, d0 + 64)) = u1;
        } else {
            us4 u0;
#pragma unroll
            for (int j = 0; j < 4; j++) {
                float xn = (vals[i * 4 + j] - mean) * inv * lw[c0 + j] + lb[c0 + j];
                u0[j] = f2bf(xn);
            }
            *reinterpret_cast<us4*>(KK + base + swzc(n, d0)) = u0;
        }
    }
}

// ---------------- v -> Vt[b][h][d][n] (pre-swizzled by d), p -> KK[:,64:128] (pre-swizzled by n) ----------------
__global__ __launch_bounds__(256) void post_vp(const float* __restrict__ vpre,
                                               const float* __restrict__ ppre,
                                               u16* __restrict__ Vt, u16* __restrict__ KK) {
    __shared__ u16 tile[64][66];
    int bh = blockIdx.x;               // 0..31
    int b = bh >> 4, h = bh & 15;
    int n0 = blockIdx.y * 64;
    int t = threadIdx.x, lane = t & 63, w = t >> 6;
#pragma unroll
    for (int j = 0; j < 4; j++) {
        int nr = t >> 2;                 // 0..63
        int d = (t & 3) * 16 + j * 4;    // 0..63
        int n = n0 + nr;
        size_t goff = ((size_t)(b * NN + n)) * 1024 + h * 64 + d;
        float4 fv = *reinterpret_cast<const float4*>(vpre + goff);
        tile[nr][d + 0] = f2bf(fv.x);
        tile[nr][d + 1] = f2bf(fv.y);
        tile[nr][d + 2] = f2bf(fv.z);
        tile[nr][d + 3] = f2bf(fv.w);
        float4 fp = *reinterpret_cast<const float4*>(ppre + goff);
        us4 up; up[0] = f2bf(fp.x); up[1] = f2bf(fp.y); up[2] = f2bf(fp.z); up[3] = f2bf(fp.w);
        *reinterpret_cast<us4*>(KK + ((size_t)(b * NH + h) * NN + n) * 128 + swzc(n, 64 + d)) = up;
    }
    __syncthreads();
    size_t vbase = (size_t)(b * NH + h) * 64 * NN;
    int n = n0 + lane;
#pragma unroll
    for (int j = 0; j < 16; j++) {
        int d = w + j * 4;
        int nsw = (n & ~127) | (((((n & 127) >> 3) ^ (d & 7)) << 3)) | (n & 7);
        Vt[vbase + (size_t)d * NN + nsw] = tile[lane][d];
    }
}

// ---------------- flash attention: S = QQ·KK^T (K=128), softmax, O = P·V ----------------
__global__ __launch_bounds__(256) void flash_attn(const u16* __restrict__ QQ,
                                                  const u16* __restrict__ KK,
                                                  const u16* __restrict__ Vt,
                                                  u16* __restrict__ ctx) {
    __shared__ u16 KKs[128 * 128];     // 32KB swizzled tile
    __shared__ u16 Vts[64 * 128];      // 16KB swizzled tile
    __shared__ u16 Ps[4][32 * 64];     // 16KB per-wave P half-strips (swizzled, row stride 64)
    int qt = blockIdx.x, h = blockIdx.y, b = blockIdx.z;
    int n0 = qt * 128;
    int t = threadIdx.x, lane = t & 63, w = t >> 6;
    int lr = lane & 15, lg = lane >> 4;
    const u16* QQg = QQ + ((size_t)(b * NH + h) * NN) * 128;
    const u16* KKg = KK + ((size_t)(b * NH + h) * NN) * 128;
    const u16* Vtg = Vt + ((size_t)(b * NH + h) * 64) * NN;

    // stage Q tile (linear 32KB copy of pre-swizzled global) into KKs
    {
        const char* src = (const char*)(QQg + (size_t)n0 * 128) + w * 8192 + lane * 16;
        char* dst = (char*)KKs + w * 8192;
#pragma unroll
        for (int i = 0; i < 8; i++)
            gload16(src + i * 1024, dst + i * 1024);
    }
    __syncthreads();
    short8 aq[2][4];
#pragma unroll
    for (int rt = 0; rt < 2; rt++)
#pragma unroll
        for (int ks = 0; ks < 4; ks++) {
            int row = w * 32 + rt * 16 + lr;
            aq[rt][ks] = *reinterpret_cast<const short8*>(
                KKs + row * 128 + (((ks * 4 + lg) ^ (row & 7)) << 3));
        }
    __syncthreads();

    f32x4 O[2][4] = {};
    float mrun[2][4], lrun[2][4];
#pragma unroll
    for (int rt = 0; rt < 2; rt++)
#pragma unroll
        for (int rg = 0; rg < 4; rg++) { mrun[rt][rg] = -1e30f; lrun[rt][rg] = 0.f; }

    for (int m0 = 0; m0 < NN; m0 += 128) {
        // stage K tile: linear 32KB
        {
            const char* src = (const char*)(KKg + (size_t)m0 * 128) + w * 8192 + lane * 16;
            char* dst = (char*)KKs + w * 8192;
#pragma unroll
            for (int i = 0; i < 8; i++)
                gload16(src + i * 1024, dst + i * 1024);
        }
        // stage V tile: 16KB, rows of 256B from strided global
        {
#pragma unroll
            for (int i = 0; i < 4; i++) {
                int oo = w * 4096 + i * 1024 + lane * 16;
                int row = oo >> 8;           // d: 0..63
                int rem = oo & 255;
                gload16((const char*)Vtg + (size_t)row * (NN * 2) + (size_t)m0 * 2 + rem,
                        (char*)Vts + w * 4096 + i * 1024);
            }
        }
        __syncthreads();
        // S = QQ·KK^T  (32 rows per wave x 128 cols), scale pre-folded into Q
        f32x4 S[2][8];
#pragma unroll
        for (int ct = 0; ct < 8; ct++) {
            short8 bk[4];
#pragma unroll
            for (int ks = 0; ks < 4; ks++) {
                int row = ct * 16 + lr;
                bk[ks] = *reinterpret_cast<const short8*>(
                    KKs + row * 128 + (((ks * 4 + lg) ^ (row & 7)) << 3));
            }
#pragma unroll
            for (int rt = 0; rt < 2; rt++) {
                f32x4 s = {};
#pragma unroll
                for (int ks = 0; ks < 4; ks++)
                    s = __builtin_amdgcn_mfma_f32_16x16x32_bf16(aq[rt][ks], bk[ks], s, 0, 0, 0);
                S[rt][ct] = s;
            }
        }
        // online softmax; rows owned by (lg, rg, rt); reduce over col lanes (lr bits)
#pragma unroll
        for (int rt = 0; rt < 2; rt++) {
#pragma unroll
            for (int rg = 0; rg < 4; rg++) {
                float mx = -1e30f;
#pragma unroll
                for (int ct = 0; ct < 8; ct++) mx = fmaxf(mx, S[rt][ct][rg]);
#pragma unroll
                for (int mk = 1; mk < 16; mk <<= 1) mx = fmaxf(mx, __shfl_xor(mx, mk));
                float newm = fmaxf(mrun[rt][rg], mx);
                float sf = __expf(mrun[rt][rg] - newm);
                float ls = 0.f;
#pragma unroll
                for (int ct = 0; ct < 8; ct++) {
                    float p = __expf(S[rt][ct][rg] - newm);
                    S[rt][ct][rg] = p;
                    ls += p;
                }
#pragma unroll
                for (int mk = 1; mk < 16; mk <<= 1) ls += __shfl_xor(ls, mk);
                lrun[rt][rg] = lrun[rt][rg] * sf + ls;
                mrun[rt][rg] = newm;
#pragma unroll
                for (int dt = 0; dt < 4; dt++) O[rt][dt][rg] *= sf;
            }
        }
        // P -> per-wave LDS half-strip [32][64], two k-halves
        u16* Pw = Ps[w];
#pragma unroll
        for (int half = 0; half < 2; half++) {
#pragma unroll
            for (int rt = 0; rt < 2; rt++)
#pragma unroll
                for (int ctl = 0; ctl < 4; ctl++) {
                    int c = ctl * 16 + lr;
#pragma unroll
                    for (int rg = 0; rg < 4; rg++) {
                        int row = rt * 16 + lg * 4 + rg;
                        Pw[row * 64 + ((((c >> 3) ^ (row & 7)) << 3) | (c & 7))] =
                            f2bf(S[rt][half * 4 + ctl][rg]);
                    }
                }
            short8 pa[2][2];
#pragma unroll
            for (int rt = 0; rt < 2; rt++)
#pragma unroll
                for (int ksl = 0; ksl < 2; ksl++) {
                    int row = rt * 16 + lr;
                    pa[rt][ksl] = *reinterpret_cast<const short8*>(
                        Pw + row * 64 + (((ksl * 4 + lg) ^ (row & 7)) << 3));
                }
#pragma unroll
            for (int dt = 0; dt < 4; dt++) {
#pragma unroll
                for (int ksl = 0; ksl < 2; ksl++) {
                    int ks = half * 2 + ksl;
                    int vrow = dt * 16 + lr;
                    short8 vf = *reinterpret_cast<const short8*>(
                        Vts + vrow * 128 + (((ks * 4 + lg) ^ (vrow & 7)) << 3));
#pragma unroll
                    for (int rt = 0; rt < 2; rt++)
                        O[rt][dt] = __builtin_amdgcn_mfma_f32_16x16x32_bf16(pa[rt][ksl], vf, O[rt][dt], 0, 0, 0);
                }
            }
        }
        __syncthreads();
    }
    // epilogue: normalize, write ctx [B*N][C] bf16 (linear layout)
#pragma unroll
    for (int rt = 0; rt < 2; rt++) {
#pragma unroll
        for (int dt = 0; dt < 4; dt++) {
#pragma unroll
            for (int rg = 0; rg < 4; rg++) {
                int n = n0 + w * 32 + rt * 16 + lg * 4 + rg;
                float oo = O[rt][dt][rg] / lrun[rt][rg];
                ctx[((size_t)(b * NN) + n) * 1024 + h * 64 + dt * 16 + lr] = f2bf(oo);
            }
        }
    }
}

extern "C" void kernel_launch(void* const* d_in, const int* in_sizes, int n_in,
                              void* d_out, int out_size, void* d_ws, size_t ws_size,
                              hipStream_t stream) {
    const float* x   = (const float*)d_in[0];
    const float* pos = (const float*)d_in[2];
    const float* Wq  = (const float*)d_in[3];
    const float* bq  = (const float*)d_in[4];
    const float* Wk  = (const float*)d_in[5];
    const float* bk  = (const float*)d_in[6];
    const float* Wv  = (const float*)d_in[7];
    const float* bv  = (const float*)d_in[8];
    const float* Wo  = (const float*)d_in[9];
    const float* bo  = (const float*)d_in[10];
    const float* qlw = (const float*)d_in[11];
    const float* qlb = (const float*)d_in[12];
    const float* klw = (const float*)d_in[13];
    const float* klb = (const float*)d_in[14];
    const float* Wp  = (const float*)d_in[15];
    const float* pbu = (const float*)d_in[16];
    const float* pbv = (const float*)d_in[17];
    float* out = (float*)d_out;

    char* ws = (char*)d_ws;
    u16*   xbf   = (u16*)(ws);                      //  8388608 B
    u16*   posbf = (u16*)(ws + 8388608);            //  8388608 B
    u16*   Wbf   = (u16*)(ws + 16777216);           //  5 x 2097152 B (q,k,v,p,o)
    float* pre   = (float*)(ws + 27262976);         //  4 x 16777216 B (q,k,v,p)
    u16*   QQ    = (u16*)(ws + 94371840);           // 16777216 B
    u16*   KK    = (u16*)(ws + 111149056);          // 16777216 B
    u16*   Vt    = (u16*)(ws + 127926272);          //  8388608 B
    u16*   ctx   = (u16*)(ws + 136314880);          //  8388608 B  (total 144703488)

    cast_kernel<<<4096, 256, 0, stream>>>(x, xbf, 1048576);
    cast_kernel<<<4096, 256, 0, stream>>>(pos, posbf, 1048576);
    cast_kernel<<<1024, 256, 0, stream>>>(Wq, Wbf + 0 * 1048576, 262144);
    cast_kernel<<<1024, 256, 0, stream>>>(Wk, Wbf + 1 * 1048576, 262144);
    cast_kernel<<<1024, 256, 0, stream>>>(Wv, Wbf + 2 * 1048576, 262144);
    cast_kernel<<<1024, 256, 0, stream>>>(Wp, Wbf + 3 * 1048576, 262144);
    cast_kernel<<<1024, 256, 0, stream>>>(Wo, Wbf + 4 * 1048576, 262144);

    proj_gemm<<<dim3(8, 32, 4), 256, 0, stream>>>(xbf, posbf, Wbf, pre, bq, bk, bv);
    post_qk<<<dim3(1024, 2), 256, 0, stream>>>(pre, qlw, qlb, klw, klb, pbu, pbv, QQ, KK);
    post_vp<<<dim3(32, 32), 256, 0, stream>>>(pre + (size_t)2 * 4194304, pre + (size_t)3 * 4194304, Vt, KK);
    flash_attn<<<dim3(16, 16, 2), 256, 0, stream>>>(QQ, KK, Vt, ctx);
    out_gemm<<<dim3(8, 32), 256, 0, stream>>>(ctx, Wbf + 4 * 1048576, out, bo);
}